// Round 11
// baseline (149.879 us; speedup 1.0000x reference)
//
#include <hip/hip_runtime.h>
#include <hip/hip_bf16.h>
#include <stdint.h>

typedef __attribute__((ext_vector_type(16))) float f32x16;
typedef __attribute__((ext_vector_type(4)))  float f32x4;
typedef __attribute__((ext_vector_type(4), aligned(4))) float f32x4u;  // 4B-aligned vec load
typedef __attribute__((ext_vector_type(8)))  __bf16 bf16x8;

#define CIN 64
#define HW 96
#define PW 98
#define OCH 128
#define NF 54
#define PCH (PW*PW)            // 9604
#define PIMG (CIN*PCH)         // 614656
#define PAD_FLOATS (8*PIMG)    // 4917248
#define PAD_BYTES ((size_t)PAD_FLOATS*4)
#define CHB 16384              // bytes per channel weight slab (128 oc x 64 k x 2B)
#define WB_BYTES ((size_t)CIN*CHB)   // 1 MiB

// ---------- pad x: [8][64][96][96] -> [8][64][98][98] zero-rimmed
__global__ __launch_bounds__(256) void prep_pad(const float* __restrict__ x,
                                                float* __restrict__ xp) {
    int idx = blockIdx.x*256 + threadIdx.x;    // grid sized exactly
    int pw_ = idx % PW;
    int t   = idx / PW;
    int ph  = t % PW;
    int ic  = t / PW;
    int h = ph - 1, w = pw_ - 1;
    float v = (((unsigned)h < HW) & ((unsigned)w < HW))
            ? x[(size_t)ic*(HW*HW) + h*HW + w] : 0.f;
    xp[idx] = v;
}

// ---------- weight prep: fp32 [oc 128][c 64][54] -> bf16 fragment-native
// elem index = ((c*4 + kc)*2 + hi)*1024 + oc*8 + i   (k = kc*16 + hi*8 + i)
__global__ __launch_bounds__(256) void prep_w(const float* __restrict__ w,
                                              __bf16* __restrict__ wb) {
    int idx = blockIdx.x * 256 + threadIdx.x;   // 262144
    int j  = idx & 31;
    int oc = (idx >> 5) & 127;
    int c  = idx >> 12;
    int k  = 2 * j;
    int kc = k >> 4, hi = (k >> 3) & 1, i = k & 7;
    float v0 = (k     < NF) ? w[(oc*CIN + c)*NF + k    ] : 0.f;
    float v1 = (k + 1 < NF) ? w[(oc*CIN + c)*NF + k + 1] : 0.f;
    size_t off = ((size_t)(c*8 + kc*2 + hi))*1024 + oc*8 + i;
    union { __bf16 b[2]; uint32_t u; } pk;
    pk.b[0] = (__bf16)v0; pk.b[1] = (__bf16)v1;
    *(uint32_t*)((char*)wb + off*2) = pk.u;
}

// cross-product pair tables (PM_cross order)
__device__ __forceinline__ constexpr int PIc(int k) {
    constexpr int t[36] = {0,1,2,3,4,5,6,7, 0,1,2,3,4,5,6, 0,1,2,3,4,5,
                           0,1,2,3,4, 0,1,2,3, 0,1,2, 0,1, 0};
    return t[k];
}
__device__ __forceinline__ constexpr int PJc(int k) {
    constexpr int t[36] = {1,2,3,4,5,6,7,8, 2,3,4,5,6,7,8, 3,4,5,6,7,8,
                           4,5,6,7,8, 5,6,7,8, 6,7,8, 7,8, 8};
    return t[k];
}

// runtime k, fully constant-folds under #pragma unroll
__device__ __forceinline__ float featv(int k, const float* q) {
    return (k < 9)  ? q[k]
         : (k < 18) ? q[k-9] * q[k-9]
         : (k < 54) ? q[PIc(k-18)] * q[PJc(k-18)]
         : 0.f;
}

// build lane's B-fragment for K-group KC (features KC*16+hi*8 .. +7), uniform code
template<int KC>
__device__ __forceinline__ bf16x8 mkfrag(const float* q, int hi) {
    uint32_t P[8];
#pragma unroll
    for (int j = 0; j < 8; j++) {
        union { __bf16 b[2]; uint32_t u; } pk;
        pk.b[0] = (__bf16)featv(KC*16 + 2*j,     q);
        pk.b[1] = (__bf16)featv(KC*16 + 2*j + 1, q);
        P[j] = pk.u;
    }
    union { uint32_t u[4]; bf16x8 v; } t;
#pragma unroll
    for (int j = 0; j < 4; j++) t.u[j] = hi ? P[4+j] : P[j];
    return t.v;
}

__device__ __forceinline__ void gload_lds16(const void* g, void* l) {
    __builtin_amdgcn_global_load_lds(
        (const __attribute__((address_space(1))) void*)g,
        (__attribute__((address_space(3))) void*)l, 16, 0, 0);
}

// ---------- main: 64 positions per wave (2 per lane) x 128 oc.
// Rationale: at 32 pos/wave, feeding the matrix pipe needs A-operand bytes at
// exactly the 128 B/cyc/CU LDS/L1 ceiling (the r8-r10 ~129us wall). 64 pos/wave
// halves A-traffic per MFMA. Block = 4 waves (16x16 tile), grid 288 -> all
// blocks resident, no serial tail. Shared LDS slab, 1 barrier/channel (at
// ~1 wave/SIMD the lockstep is harmless - no cross-wave filling exists).
// mfma_f32_32x32x16_bf16: A/B lane: row/col = lane&31, k = (lane>>5)*8+i;
// D: col = lane&31, row = (reg&3) + 8*(reg>>2) + 4*(lane>>5).
__global__ __launch_bounds__(256, 2) void socg_w64(const float* __restrict__ xp,
                                                   const __bf16* __restrict__ wb,
                                                   float* __restrict__ out) {
    __shared__ __align__(16) char sw[2][CHB];   // 32 KiB double-buffered slab

    const int tid  = threadIdx.x;
    const int lane = tid & 63;
    const int wv   = tid >> 6;
    const int hi   = lane >> 5;
    const int l31  = lane & 31;

    const int bid  = blockIdx.x;        // 288 = 8 imgs * 36 tiles
    const int bimg = bid & 7;           // XCD k -> image k (L2 locality)
    const int rem  = bid >> 3;          // 0..35
    const int h0   = (rem / 6) * 16;    // block tile: 16x16
    const int w0   = (rem % 6) * 16;

    // lane's two positions: (r0, c0) [pt0] and (r0+2, c0) [pt1]
    const int r0 = h0 + wv*4 + (l31 >> 4);
    const int c0 = w0 + (l31 & 15);

    const char* xbase = (const char*)(xp + (size_t)bimg*PIMG);
    const int voff0 = (r0*PW + c0) * 4;   // padded addr of window row j: + j*PW*4

    f32x16 acc[2][4];
#pragma unroll
    for (int pt = 0; pt < 2; pt++)
#pragma unroll
        for (int os = 0; os < 4; os++)
#pragma unroll
            for (int r = 0; r < 16; r++) acc[pt][os][r] = 0.f;

    // prologue: stage channel 0, load channel-0 window (5 rows x f32x4)
    {
        const char* wsrc = (const char*)wb;
#pragma unroll
        for (int i = 0; i < 4; i++) {
            const int m = i*4 + wv;
            gload_lds16(wsrc + m*1024 + lane*16, &sw[0][0] + m*1024);
        }
    }
    f32x4 R0[5], R1[5];
#pragma unroll
    for (int j = 0; j < 5; j++)
        R0[j] = (f32x4)*(const f32x4u*)(xbase + voff0 + j*(PW*4));
    __syncthreads();

    auto chan = [&](f32x4 (&Rc)[5], f32x4 (&Rn)[5], int c) {
        char* bufc = &sw[0][0] + ((c    ) & 1) * CHB;
        char* bufn = &sw[0][0] + ((c + 1) & 1) * CHB;
        // 1) issue next-channel staging + window prefetch
        if (c + 1 < CIN) {
            const char* wsrc = (const char*)wb + (size_t)(c + 1)*CHB;
#pragma unroll
            for (int i = 0; i < 4; i++) {
                const int m = i*4 + wv;
                gload_lds16(wsrc + m*1024 + lane*16, bufn + m*1024);
            }
            const char* xn = xbase + (size_t)(c + 1)*(PCH*4);
#pragma unroll
            for (int j = 0; j < 5; j++)
                Rn[j] = (f32x4)*(const f32x4u*)(xn + voff0 + j*(PW*4));
        }
        // 2) A-frags kc0,kc1 (ds_read latency hides under build)
        bf16x8 A0[4], A1[4];
#pragma unroll
        for (int os = 0; os < 4; os++) {
            const int co = (os*32 + l31)*16;
            A0[os] = *(const bf16x8*)(bufc + (0*2 + hi)*2048 + co);
            A1[os] = *(const bf16x8*)(bufc + (1*2 + hi)*2048 + co);
        }
        // 3) windows for the two positions (share row r0+1)
        float q0[9], q1[9];
#pragma unroll
        for (int j = 0; j < 3; j++) {
            q0[j*3 + 0] = Rc[j][0];   q0[j*3 + 1] = Rc[j][1];   q0[j*3 + 2] = Rc[j][2];
            q1[j*3 + 0] = Rc[j+2][0]; q1[j*3 + 1] = Rc[j+2][1]; q1[j*3 + 2] = Rc[j+2][2];
        }
        // 4) kc loop: 2 B-builds + 8 MFMA each; A regs recycled kc0->kc2, kc1->kc3
        {
            bf16x8 t0 = mkfrag<0>(q0, hi), t1 = mkfrag<0>(q1, hi);
#pragma unroll
            for (int os = 0; os < 4; os++) {
                acc[0][os] = __builtin_amdgcn_mfma_f32_32x32x16_bf16(A0[os], t0, acc[0][os], 0, 0, 0);
                acc[1][os] = __builtin_amdgcn_mfma_f32_32x32x16_bf16(A0[os], t1, acc[1][os], 0, 0, 0);
            }
        }
#pragma unroll
        for (int os = 0; os < 4; os++)
            A0[os] = *(const bf16x8*)(bufc + (2*2 + hi)*2048 + (os*32 + l31)*16);
        {
            bf16x8 t0 = mkfrag<1>(q0, hi), t1 = mkfrag<1>(q1, hi);
#pragma unroll
            for (int os = 0; os < 4; os++) {
                acc[0][os] = __builtin_amdgcn_mfma_f32_32x32x16_bf16(A1[os], t0, acc[0][os], 0, 0, 0);
                acc[1][os] = __builtin_amdgcn_mfma_f32_32x32x16_bf16(A1[os], t1, acc[1][os], 0, 0, 0);
            }
        }
#pragma unroll
        for (int os = 0; os < 4; os++)
            A1[os] = *(const bf16x8*)(bufc + (3*2 + hi)*2048 + (os*32 + l31)*16);
        {
            bf16x8 t0 = mkfrag<2>(q0, hi), t1 = mkfrag<2>(q1, hi);
#pragma unroll
            for (int os = 0; os < 4; os++) {
                acc[0][os] = __builtin_amdgcn_mfma_f32_32x32x16_bf16(A0[os], t0, acc[0][os], 0, 0, 0);
                acc[1][os] = __builtin_amdgcn_mfma_f32_32x32x16_bf16(A0[os], t1, acc[1][os], 0, 0, 0);
            }
        }
        {
            bf16x8 t0 = mkfrag<3>(q0, hi), t1 = mkfrag<3>(q1, hi);
#pragma unroll
            for (int os = 0; os < 4; os++) {
                acc[0][os] = __builtin_amdgcn_mfma_f32_32x32x16_bf16(A1[os], t0, acc[0][os], 0, 0, 0);
                acc[1][os] = __builtin_amdgcn_mfma_f32_32x32x16_bf16(A1[os], t1, acc[1][os], 0, 0, 0);
            }
        }
        // 5) barrier: my slab reads done + stage(c+1) landed (vmcnt drain covered
        //    by the ~1300 cycles of build+MFMA above)
        __syncthreads();
    };

#pragma unroll 1
    for (int c2 = 0; c2 < CIN; c2 += 2) {
        chan(R0, R1, c2);
        chan(R1, R0, c2 + 1);
    }

    // epilogue: D col = pos (lane&31), row = (r&3) + 8*(r>>2) + 4*hi
    const size_t ibase = (size_t)bimg*OCH*HW*HW;
#pragma unroll
    for (int pt = 0; pt < 2; pt++) {
        const size_t obase = ibase + (size_t)(r0 + 2*pt)*HW + c0;
#pragma unroll
        for (int os = 0; os < 4; os++)
#pragma unroll
            for (int r = 0; r < 16; r++) {
                const int oc = os*32 + (r & 3) + 8*(r >> 2) + 4*hi;
                out[obase + (size_t)oc*(HW*HW)] = acc[pt][os][r];
            }
    }
}

// ---------- fallback (no pad buffer): round-8 register-path kernel
__global__ __launch_bounds__(64, 3) void socg_fb(const float* __restrict__ x,
                                                 const __bf16* __restrict__ wb,
                                                 float* __restrict__ out) {
    const int lane = threadIdx.x;
    const int hi   = lane >> 5;
    const int l31  = lane & 31;

    const int bid  = blockIdx.x;
    const int bimg = bid / 288;
    const int rem  = bid - bimg * 288;
    const int h0   = (rem / 6) * 2;
    const int w0   = (rem % 6) * 16;

    const int hA = h0 + (l31 >> 4);
    const int wA = w0 + (l31 & 15);

    int   off[9];
    float msk[9];
#pragma unroll
    for (int rr = 0; rr < 3; rr++)
#pragma unroll
        for (int cc = 0; cc < 3; cc++) {
            int hh = hA - 1 + rr, ww = wA - 1 + cc;
            bool ok = ((unsigned)hh < HW) && ((unsigned)ww < HW);
            int hc = hh < 0 ? 0 : (hh > HW-1 ? HW-1 : hh);
            int wc = ww < 0 ? 0 : (ww > HW-1 ? HW-1 : ww);
            off[rr*3 + cc] = hc * HW + wc;
            msk[rr*3 + cc] = ok ? 1.f : 0.f;
        }

    const float* xb = x + (size_t)bimg * CIN * HW * HW;

    f32x16 acc[4];
#pragma unroll
    for (int os = 0; os < 4; os++)
#pragma unroll
        for (int r = 0; r < 16; r++) acc[os][r] = 0.f;

    float rA[9], rB[9];
#pragma unroll
    for (int i = 0; i < 9; i++) rA[i] = xb[off[i]];

    auto loadA = [&](bf16x8 (&A)[4], const __bf16* wc_, int kc) {
#pragma unroll
        for (int os = 0; os < 4; os++)
            A[os] = *(const bf16x8*)(wc_ + (kc*2 + hi)*1024 + (os*32 + l31)*8);
    };

    auto body = [&](float (&rc)[9], float (&rn)[9], int c) {
        const __bf16* wc_ = wb + (size_t)c * 8192;
        bf16x8 A0[4], A1[4], A2[4], A3[4];
        loadA(A0, wc_, 0);
        loadA(A1, wc_, 1);
        loadA(A2, wc_, 2);
        loadA(A3, wc_, 3);
        if (c + 1 < CIN) {
            const float* xn = xb + (size_t)(c + 1) * HW * HW;
#pragma unroll
            for (int i = 0; i < 9; i++) rn[i] = xn[off[i]];
        }
        float q[9];
#pragma unroll
        for (int i = 0; i < 9; i++) q[i] = rc[i] * msk[i];

        {
            bf16x8 tb = mkfrag<0>(q, hi);
#pragma unroll
            for (int os = 0; os < 4; os++)
                acc[os] = __builtin_amdgcn_mfma_f32_32x32x16_bf16(A0[os], tb, acc[os], 0, 0, 0);
        }
        {
            bf16x8 tb = mkfrag<1>(q, hi);
#pragma unroll
            for (int os = 0; os < 4; os++)
                acc[os] = __builtin_amdgcn_mfma_f32_32x32x16_bf16(A1[os], tb, acc[os], 0, 0, 0);
        }
        {
            bf16x8 tb = mkfrag<2>(q, hi);
#pragma unroll
            for (int os = 0; os < 4; os++)
                acc[os] = __builtin_amdgcn_mfma_f32_32x32x16_bf16(A2[os], tb, acc[os], 0, 0, 0);
        }
        {
            bf16x8 tb = mkfrag<3>(q, hi);
#pragma unroll
            for (int os = 0; os < 4; os++)
                acc[os] = __builtin_amdgcn_mfma_f32_32x32x16_bf16(A3[os], tb, acc[os], 0, 0, 0);
        }
    };

#pragma unroll 1
    for (int c2 = 0; c2 < CIN; c2 += 2) {
        body(rA, rB, c2);
        body(rB, rA, c2 + 1);
    }

#pragma unroll
    for (int os = 0; os < 4; os++)
#pragma unroll
        for (int r = 0; r < 16; r++) {
            int oc = os*32 + (r & 3) + 8*(r >> 2) + 4*hi;
            out[(((size_t)bimg*OCH + oc)*HW + hA)*HW + wA] = acc[os][r];
        }
}

extern "C" void kernel_launch(void* const* d_in, const int* in_sizes, int n_in,
                              void* d_out, int out_size, void* d_ws, size_t ws_size,
                              hipStream_t stream) {
    const float* x = (const float*)d_in[0];
    const float* w = (const float*)d_in[1];
    float* out = (float*)d_out;
    if (ws_size >= PAD_BYTES + WB_BYTES) {
        float* xpad = (float*)d_ws;
        __bf16* wbf = (__bf16*)((char*)d_ws + PAD_BYTES);
        hipLaunchKernelGGL(prep_pad, dim3(PAD_FLOATS/256), dim3(256), 0, stream, x, xpad);
        hipLaunchKernelGGL(prep_w, dim3(1024), dim3(256), 0, stream, w, wbf);
        hipLaunchKernelGGL(socg_w64, dim3(288), dim3(256), 0, stream, xpad, wbf, out);
    } else {
        __bf16* wbf = (__bf16*)d_ws;
        hipLaunchKernelGGL(prep_w, dim3(1024), dim3(256), 0, stream, w, wbf);
        hipLaunchKernelGGL(socg_fb, dim3(2304), dim3(64), 0, stream, x, wbf, out);
    }
}

// Round 12
// 149.701 us; speedup vs baseline: 1.0012x; 1.0012x over previous
//
#include <hip/hip_runtime.h>
#include <hip/hip_bf16.h>
#include <stdint.h>

typedef __attribute__((ext_vector_type(16))) float f32x16;
typedef __attribute__((ext_vector_type(4)))  float f32x4;
typedef __attribute__((ext_vector_type(4), aligned(4))) float f32x4u;  // 4B-aligned vec load
typedef __attribute__((ext_vector_type(8)))  __bf16 bf16x8;

#define CIN 64
#define HW 96
#define PW 98
#define OCH 128
#define NF 54
#define PCH (PW*PW)            // 9604
#define PIMG (CIN*PCH)         // 614656
#define PAD_FLOATS (8*PIMG)    // 4917248
#define PAD_BYTES ((size_t)PAD_FLOATS*4)
#define CHB 16384              // bytes per channel weight slab (128 oc x 64 k x 2B)
#define WB_BYTES ((size_t)CIN*CHB)   // 1 MiB

// ---------- pad x: [8][64][96][96] -> [8][64][98][98] zero-rimmed
__global__ __launch_bounds__(256) void prep_pad(const float* __restrict__ x,
                                                float* __restrict__ xp) {
    int idx = blockIdx.x*256 + threadIdx.x;    // grid sized exactly
    int pw_ = idx % PW;
    int t   = idx / PW;
    int ph  = t % PW;
    int ic  = t / PW;
    int h = ph - 1, w = pw_ - 1;
    float v = (((unsigned)h < HW) & ((unsigned)w < HW))
            ? x[(size_t)ic*(HW*HW) + h*HW + w] : 0.f;
    xp[idx] = v;
}

// ---------- weight prep: fp32 [oc 128][c 64][54] -> bf16 fragment-native
// elem index = ((c*4 + kc)*2 + hi)*1024 + oc*8 + i   (k = kc*16 + hi*8 + i)
__global__ __launch_bounds__(256) void prep_w(const float* __restrict__ w,
                                              __bf16* __restrict__ wb) {
    int idx = blockIdx.x * 256 + threadIdx.x;   // 262144
    int j  = idx & 31;
    int oc = (idx >> 5) & 127;
    int c  = idx >> 12;
    int k  = 2 * j;
    int kc = k >> 4, hi = (k >> 3) & 1, i = k & 7;
    float v0 = (k     < NF) ? w[(oc*CIN + c)*NF + k    ] : 0.f;
    float v1 = (k + 1 < NF) ? w[(oc*CIN + c)*NF + k + 1] : 0.f;
    size_t off = ((size_t)(c*8 + kc*2 + hi))*1024 + oc*8 + i;
    union { __bf16 b[2]; uint32_t u; } pk;
    pk.b[0] = (__bf16)v0; pk.b[1] = (__bf16)v1;
    *(uint32_t*)((char*)wb + off*2) = pk.u;
}

// cross-product pair tables (PM_cross order)
__device__ __forceinline__ constexpr int PIc(int k) {
    constexpr int t[36] = {0,1,2,3,4,5,6,7, 0,1,2,3,4,5,6, 0,1,2,3,4,5,
                           0,1,2,3,4, 0,1,2,3, 0,1,2, 0,1, 0};
    return t[k];
}
__device__ __forceinline__ constexpr int PJc(int k) {
    constexpr int t[36] = {1,2,3,4,5,6,7,8, 2,3,4,5,6,7,8, 3,4,5,6,7,8,
                           4,5,6,7,8, 5,6,7,8, 6,7,8, 7,8, 8};
    return t[k];
}

// runtime k, fully constant-folds under #pragma unroll
__device__ __forceinline__ float featv(int k, const float* q) {
    return (k < 9)  ? q[k]
         : (k < 18) ? q[k-9] * q[k-9]
         : (k < 54) ? q[PIc(k-18)] * q[PJc(k-18)]
         : 0.f;
}

// build lane's B-fragment for K-group KC (features KC*16+hi*8 .. +7), uniform code
template<int KC>
__device__ __forceinline__ bf16x8 mkfrag(const float* q, int hi) {
    uint32_t P[8];
#pragma unroll
    for (int j = 0; j < 8; j++) {
        union { __bf16 b[2]; uint32_t u; } pk;
        pk.b[0] = (__bf16)featv(KC*16 + 2*j,     q);
        pk.b[1] = (__bf16)featv(KC*16 + 2*j + 1, q);
        P[j] = pk.u;
    }
    union { uint32_t u[4]; bf16x8 v; } t;
#pragma unroll
    for (int j = 0; j < 4; j++) t.u[j] = hi ? P[4+j] : P[j];
    return t.v;
}

__device__ __forceinline__ void gload_lds16(const void* g, void* l) {
    __builtin_amdgcn_global_load_lds(
        (const __attribute__((address_space(1))) void*)g,
        (__attribute__((address_space(3))) void*)l, 16, 0, 0);
}

// ---------- main: 64 positions per wave (2 per lane) x 128 oc.
// Rationale: at 32 pos/wave, feeding the matrix pipe needs A-operand bytes at
// exactly the 128 B/cyc/CU LDS/L1 ceiling (the r8-r10 ~129us wall). 64 pos/wave
// halves A-traffic per MFMA. Block = 4 waves (16x16 tile), grid 288 -> all
// blocks resident, no serial tail. Shared LDS slab, 1 barrier/channel (at
// ~1 wave/SIMD the lockstep is harmless - no cross-wave filling exists).
// mfma_f32_32x32x16_bf16: A/B lane: row/col = lane&31, k = (lane>>5)*8+i;
// D: col = lane&31, row = (reg&3) + 8*(reg>>2) + 4*(lane>>5).
__global__ __launch_bounds__(256, 2) void socg_w64(const float* __restrict__ xp,
                                                   const __bf16* __restrict__ wb,
                                                   float* __restrict__ out) {
    __shared__ __align__(16) char sw[2][CHB];   // 32 KiB double-buffered slab

    const int tid  = threadIdx.x;
    const int lane = tid & 63;
    const int wv   = tid >> 6;
    const int hi   = lane >> 5;
    const int l31  = lane & 31;

    const int bid  = blockIdx.x;        // 288 = 8 imgs * 36 tiles
    const int bimg = bid & 7;           // XCD k -> image k (L2 locality)
    const int rem  = bid >> 3;          // 0..35
    const int h0   = (rem / 6) * 16;    // block tile: 16x16
    const int w0   = (rem % 6) * 16;

    // lane's two positions: (r0, c0) [pt0] and (r0+2, c0) [pt1]
    const int r0 = h0 + wv*4 + (l31 >> 4);
    const int c0 = w0 + (l31 & 15);

    const char* xbase = (const char*)(xp + (size_t)bimg*PIMG);
    const int voff0 = (r0*PW + c0) * 4;   // padded addr of window row j: + j*PW*4

    f32x16 acc[2][4];
#pragma unroll
    for (int pt = 0; pt < 2; pt++)
#pragma unroll
        for (int os = 0; os < 4; os++)
#pragma unroll
            for (int r = 0; r < 16; r++) acc[pt][os][r] = 0.f;

    // prologue: stage channel 0, load channel-0 window (5 rows x f32x4)
    {
        const char* wsrc = (const char*)wb;
#pragma unroll
        for (int i = 0; i < 4; i++) {
            const int m = i*4 + wv;
            gload_lds16(wsrc + m*1024 + lane*16, &sw[0][0] + m*1024);
        }
    }
    f32x4 R0[5], R1[5];
#pragma unroll
    for (int j = 0; j < 5; j++)
        R0[j] = (f32x4)*(const f32x4u*)(xbase + voff0 + j*(PW*4));
    __syncthreads();

    auto chan = [&](f32x4 (&Rc)[5], f32x4 (&Rn)[5], int c) {
        char* bufc = &sw[0][0] + ((c    ) & 1) * CHB;
        char* bufn = &sw[0][0] + ((c + 1) & 1) * CHB;
        // 1) issue next-channel staging + window prefetch
        if (c + 1 < CIN) {
            const char* wsrc = (const char*)wb + (size_t)(c + 1)*CHB;
#pragma unroll
            for (int i = 0; i < 4; i++) {
                const int m = i*4 + wv;
                gload_lds16(wsrc + m*1024 + lane*16, bufn + m*1024);
            }
            const char* xn = xbase + (size_t)(c + 1)*(PCH*4);
#pragma unroll
            for (int j = 0; j < 5; j++)
                Rn[j] = (f32x4)*(const f32x4u*)(xn + voff0 + j*(PW*4));
        }
        // 2) A-frags kc0,kc1 (ds_read latency hides under build)
        bf16x8 A0[4], A1[4];
#pragma unroll
        for (int os = 0; os < 4; os++) {
            const int co = (os*32 + l31)*16;
            A0[os] = *(const bf16x8*)(bufc + (0*2 + hi)*2048 + co);
            A1[os] = *(const bf16x8*)(bufc + (1*2 + hi)*2048 + co);
        }
        // 3) windows for the two positions (share row r0+1)
        float q0[9], q1[9];
#pragma unroll
        for (int j = 0; j < 3; j++) {
            q0[j*3 + 0] = Rc[j][0];   q0[j*3 + 1] = Rc[j][1];   q0[j*3 + 2] = Rc[j][2];
            q1[j*3 + 0] = Rc[j+2][0]; q1[j*3 + 1] = Rc[j+2][1]; q1[j*3 + 2] = Rc[j+2][2];
        }
        // 4) kc loop: 2 B-builds + 8 MFMA each; A regs recycled kc0->kc2, kc1->kc3
        {
            bf16x8 t0 = mkfrag<0>(q0, hi), t1 = mkfrag<0>(q1, hi);
#pragma unroll
            for (int os = 0; os < 4; os++) {
                acc[0][os] = __builtin_amdgcn_mfma_f32_32x32x16_bf16(A0[os], t0, acc[0][os], 0, 0, 0);
                acc[1][os] = __builtin_amdgcn_mfma_f32_32x32x16_bf16(A0[os], t1, acc[1][os], 0, 0, 0);
            }
        }
#pragma unroll
        for (int os = 0; os < 4; os++)
            A0[os] = *(const bf16x8*)(bufc + (2*2 + hi)*2048 + (os*32 + l31)*16);
        {
            bf16x8 t0 = mkfrag<1>(q0, hi), t1 = mkfrag<1>(q1, hi);
#pragma unroll
            for (int os = 0; os < 4; os++) {
                acc[0][os] = __builtin_amdgcn_mfma_f32_32x32x16_bf16(A1[os], t0, acc[0][os], 0, 0, 0);
                acc[1][os] = __builtin_amdgcn_mfma_f32_32x32x16_bf16(A1[os], t1, acc[1][os], 0, 0, 0);
            }
        }
#pragma unroll
        for (int os = 0; os < 4; os++)
            A1[os] = *(const bf16x8*)(bufc + (3*2 + hi)*2048 + (os*32 + l31)*16);
        {
            bf16x8 t0 = mkfrag<2>(q0, hi), t1 = mkfrag<2>(q1, hi);
#pragma unroll
            for (int os = 0; os < 4; os++) {
                acc[0][os] = __builtin_amdgcn_mfma_f32_32x32x16_bf16(A0[os], t0, acc[0][os], 0, 0, 0);
                acc[1][os] = __builtin_amdgcn_mfma_f32_32x32x16_bf16(A0[os], t1, acc[1][os], 0, 0, 0);
            }
        }
        {
            bf16x8 t0 = mkfrag<3>(q0, hi), t1 = mkfrag<3>(q1, hi);
#pragma unroll
            for (int os = 0; os < 4; os++) {
                acc[0][os] = __builtin_amdgcn_mfma_f32_32x32x16_bf16(A1[os], t0, acc[0][os], 0, 0, 0);
                acc[1][os] = __builtin_amdgcn_mfma_f32_32x32x16_bf16(A1[os], t1, acc[1][os], 0, 0, 0);
            }
        }
        // 5) barrier: my slab reads done + stage(c+1) landed (vmcnt drain covered
        //    by the ~1300 cycles of build+MFMA above)
        __syncthreads();
    };

#pragma unroll 1
    for (int c2 = 0; c2 < CIN; c2 += 2) {
        chan(R0, R1, c2);
        chan(R1, R0, c2 + 1);
    }

    // epilogue: D col = pos (lane&31), row = (r&3) + 8*(r>>2) + 4*hi
    const size_t ibase = (size_t)bimg*OCH*HW*HW;
#pragma unroll
    for (int pt = 0; pt < 2; pt++) {
        const size_t obase = ibase + (size_t)(r0 + 2*pt)*HW + c0;
#pragma unroll
        for (int os = 0; os < 4; os++)
#pragma unroll
            for (int r = 0; r < 16; r++) {
                const int oc = os*32 + (r & 3) + 8*(r >> 2) + 4*hi;
                out[obase + (size_t)oc*(HW*HW)] = acc[pt][os][r];
            }
    }
}

// ---------- fallback (no pad buffer): round-8 register-path kernel
__global__ __launch_bounds__(64, 3) void socg_fb(const float* __restrict__ x,
                                                 const __bf16* __restrict__ wb,
                                                 float* __restrict__ out) {
    const int lane = threadIdx.x;
    const int hi   = lane >> 5;
    const int l31  = lane & 31;

    const int bid  = blockIdx.x;
    const int bimg = bid / 288;
    const int rem  = bid - bimg * 288;
    const int h0   = (rem / 6) * 2;
    const int w0   = (rem % 6) * 16;

    const int hA = h0 + (l31 >> 4);
    const int wA = w0 + (l31 & 15);

    int   off[9];
    float msk[9];
#pragma unroll
    for (int rr = 0; rr < 3; rr++)
#pragma unroll
        for (int cc = 0; cc < 3; cc++) {
            int hh = hA - 1 + rr, ww = wA - 1 + cc;
            bool ok = ((unsigned)hh < HW) && ((unsigned)ww < HW);
            int hc = hh < 0 ? 0 : (hh > HW-1 ? HW-1 : hh);
            int wc = ww < 0 ? 0 : (ww > HW-1 ? HW-1 : ww);
            off[rr*3 + cc] = hc * HW + wc;
            msk[rr*3 + cc] = ok ? 1.f : 0.f;
        }

    const float* xb = x + (size_t)bimg * CIN * HW * HW;

    f32x16 acc[4];
#pragma unroll
    for (int os = 0; os < 4; os++)
#pragma unroll
        for (int r = 0; r < 16; r++) acc[os][r] = 0.f;

    float rA[9], rB[9];
#pragma unroll
    for (int i = 0; i < 9; i++) rA[i] = xb[off[i]];

    auto loadA = [&](bf16x8 (&A)[4], const __bf16* wc_, int kc) {
#pragma unroll
        for (int os = 0; os < 4; os++)
            A[os] = *(const bf16x8*)(wc_ + (kc*2 + hi)*1024 + (os*32 + l31)*8);
    };

    auto body = [&](float (&rc)[9], float (&rn)[9], int c) {
        const __bf16* wc_ = wb + (size_t)c * 8192;
        bf16x8 A0[4], A1[4], A2[4], A3[4];
        loadA(A0, wc_, 0);
        loadA(A1, wc_, 1);
        loadA(A2, wc_, 2);
        loadA(A3, wc_, 3);
        if (c + 1 < CIN) {
            const float* xn = xb + (size_t)(c + 1) * HW * HW;
#pragma unroll
            for (int i = 0; i < 9; i++) rn[i] = xn[off[i]];
        }
        float q[9];
#pragma unroll
        for (int i = 0; i < 9; i++) q[i] = rc[i] * msk[i];

        {
            bf16x8 tb = mkfrag<0>(q, hi);
#pragma unroll
            for (int os = 0; os < 4; os++)
                acc[os] = __builtin_amdgcn_mfma_f32_32x32x16_bf16(A0[os], tb, acc[os], 0, 0, 0);
        }
        {
            bf16x8 tb = mkfrag<1>(q, hi);
#pragma unroll
            for (int os = 0; os < 4; os++)
                acc[os] = __builtin_amdgcn_mfma_f32_32x32x16_bf16(A1[os], tb, acc[os], 0, 0, 0);
        }
        {
            bf16x8 tb = mkfrag<2>(q, hi);
#pragma unroll
            for (int os = 0; os < 4; os++)
                acc[os] = __builtin_amdgcn_mfma_f32_32x32x16_bf16(A2[os], tb, acc[os], 0, 0, 0);
        }
        {
            bf16x8 tb = mkfrag<3>(q, hi);
#pragma unroll
            for (int os = 0; os < 4; os++)
                acc[os] = __builtin_amdgcn_mfma_f32_32x32x16_bf16(A3[os], tb, acc[os], 0, 0, 0);
        }
    };

#pragma unroll 1
    for (int c2 = 0; c2 < CIN; c2 += 2) {
        body(rA, rB, c2);
        body(rB, rA, c2 + 1);
    }

#pragma unroll
    for (int os = 0; os < 4; os++)
#pragma unroll
        for (int r = 0; r < 16; r++) {
            int oc = os*32 + (r & 3) + 8*(r >> 2) + 4*hi;
            out[(((size_t)bimg*OCH + oc)*HW + hA)*HW + wA] = acc[os][r];
        }
}

extern "C" void kernel_launch(void* const* d_in, const int* in_sizes, int n_in,
                              void* d_out, int out_size, void* d_ws, size_t ws_size,
                              hipStream_t stream) {
    const float* x = (const float*)d_in[0];
    const float* w = (const float*)d_in[1];
    float* out = (float*)d_out;
    if (ws_size >= PAD_BYTES + WB_BYTES) {
        float* xpad = (float*)d_ws;
        __bf16* wbf = (__bf16*)((char*)d_ws + PAD_BYTES);
        hipLaunchKernelGGL(prep_pad, dim3(PAD_FLOATS/256), dim3(256), 0, stream, x, xpad);
        hipLaunchKernelGGL(prep_w, dim3(1024), dim3(256), 0, stream, w, wbf);
        hipLaunchKernelGGL(socg_w64, dim3(288), dim3(256), 0, stream, xpad, wbf, out);
    } else {
        __bf16* wbf = (__bf16*)d_ws;
        hipLaunchKernelGGL(prep_w, dim3(1024), dim3(256), 0, stream, w, wbf);
        hipLaunchKernelGGL(socg_fb, dim3(2304), dim3(64), 0, stream, x, wbf, out);
    }
}

// Round 13
// 130.424 us; speedup vs baseline: 1.1492x; 1.1478x over previous
//
#include <hip/hip_runtime.h>
#include <hip/hip_bf16.h>
#include <stdint.h>

typedef __attribute__((ext_vector_type(16))) float f32x16;
typedef __attribute__((ext_vector_type(4)))  float f32x4;
typedef __attribute__((ext_vector_type(4), aligned(4))) float f32x4u;  // 4B-aligned vec load
typedef __attribute__((ext_vector_type(8)))  __bf16 bf16x8;

#define CIN 64
#define HW 96
#define PW 98
#define OCH 128
#define NF 54
#define PCH (PW*PW)            // 9604
#define PIMG (CIN*PCH)         // 614656
#define PAD_FLOATS (8*PIMG)    // 4917248
#define PAD_BYTES ((size_t)PAD_FLOATS*4)
#define CHB 16384              // bytes per channel weight slab (128 oc x 64 k x 2B)
#define WB_BYTES ((size_t)CIN*CHB)   // 1 MiB

// ---------- pad x: [8][64][96][96] -> [8][64][98][98] zero-rimmed
__global__ __launch_bounds__(256) void prep_pad(const float* __restrict__ x,
                                                float* __restrict__ xp) {
    int idx = blockIdx.x*256 + threadIdx.x;    // grid sized exactly
    int pw_ = idx % PW;
    int t   = idx / PW;
    int ph  = t % PW;
    int ic  = t / PW;
    int h = ph - 1, w = pw_ - 1;
    float v = (((unsigned)h < HW) & ((unsigned)w < HW))
            ? x[(size_t)ic*(HW*HW) + h*HW + w] : 0.f;
    xp[idx] = v;
}

// ---------- weight prep: fp32 [oc 128][c 64][54] -> bf16 fragment-native
// elem index = ((c*4 + kc)*2 + hi)*1024 + oc*8 + i   (k = kc*16 + hi*8 + i)
__global__ __launch_bounds__(256) void prep_w(const float* __restrict__ w,
                                              __bf16* __restrict__ wb) {
    int idx = blockIdx.x * 256 + threadIdx.x;   // 262144
    int j  = idx & 31;
    int oc = (idx >> 5) & 127;
    int c  = idx >> 12;
    int k  = 2 * j;
    int kc = k >> 4, hi = (k >> 3) & 1, i = k & 7;
    float v0 = (k     < NF) ? w[(oc*CIN + c)*NF + k    ] : 0.f;
    float v1 = (k + 1 < NF) ? w[(oc*CIN + c)*NF + k + 1] : 0.f;
    size_t off = ((size_t)(c*8 + kc*2 + hi))*1024 + oc*8 + i;
    union { __bf16 b[2]; uint32_t u; } pk;
    pk.b[0] = (__bf16)v0; pk.b[1] = (__bf16)v1;
    *(uint32_t*)((char*)wb + off*2) = pk.u;
}

// cross-product pair tables (PM_cross order)
__device__ __forceinline__ constexpr int PIc(int k) {
    constexpr int t[36] = {0,1,2,3,4,5,6,7, 0,1,2,3,4,5,6, 0,1,2,3,4,5,
                           0,1,2,3,4, 0,1,2,3, 0,1,2, 0,1, 0};
    return t[k];
}
__device__ __forceinline__ constexpr int PJc(int k) {
    constexpr int t[36] = {1,2,3,4,5,6,7,8, 2,3,4,5,6,7,8, 3,4,5,6,7,8,
                           4,5,6,7,8, 5,6,7,8, 6,7,8, 7,8, 8};
    return t[k];
}

// runtime k, fully constant-folds under #pragma unroll
__device__ __forceinline__ float featv(int k, const float* q) {
    return (k < 9)  ? q[k]
         : (k < 18) ? q[k-9] * q[k-9]
         : (k < 54) ? q[PIc(k-18)] * q[PJc(k-18)]
         : 0.f;
}

// build lane's B-fragment for K-group KC (features KC*16+hi*8 .. +7), uniform code
template<int KC>
__device__ __forceinline__ bf16x8 mkfrag(const float* q, int hi) {
    uint32_t P[8];
#pragma unroll
    for (int j = 0; j < 8; j++) {
        union { __bf16 b[2]; uint32_t u; } pk;
        pk.b[0] = (__bf16)featv(KC*16 + 2*j,     q);
        pk.b[1] = (__bf16)featv(KC*16 + 2*j + 1, q);
        P[j] = pk.u;
    }
    union { uint32_t u[4]; bf16x8 v; } t;
#pragma unroll
    for (int j = 0; j < 4; j++) t.u[j] = hi ? P[4+j] : P[j];
    return t.v;
}

__device__ __forceinline__ void gload_lds16(const void* g, void* l) {
    __builtin_amdgcn_global_load_lds(
        (const __attribute__((address_space(1))) void*)g,
        (__attribute__((address_space(3))) void*)l, 16, 0, 0);
}

// ---------- main: K-split for occupancy. Block = 512 thr = 8 waves =
// 4 pos-groups x 2 K-halves. Wave = 32 pos x 128 oc, processes 32 channels
// (half h: channels h*32 .. h*32+31). 4608 waves total = 4.5/SIMD target;
// __launch_bounds__(512,4) caps regs at 128/wave (acc 64 AGPR + ~60 VGPR:
// single A-set per kc, single-buffered R window, no prefetch - occupancy
// hides latency). Weight slabs: per-half LDS double-buffer (64 KB/block).
// R loads are issued BEFORE the staging gload_lds so the build's waitcnt is
// vmcnt(4) (staging stays in flight; drained only at the barrier).
// XOR ownership: local acc block os = global oc block (os ^ (h<<1)); K-combine
// via LDS with partner wave (wv^4). All acc subscripts compile-time (rule #20).
// mfma_f32_32x32x16_bf16: A/B lane: row/col = lane&31, k = (lane>>5)*8+i;
// D: col = lane&31, row = (reg&3) + 8*(reg>>2) + 4*(lane>>5).
__global__ __launch_bounds__(512, 4) void socg_ks(const float* __restrict__ xp,
                                                  const __bf16* __restrict__ wb,
                                                  float* __restrict__ out) {
    __shared__ __align__(16) char sw[2][2][CHB];   // [half][dbuf][slab] = 64 KiB

    const int tid  = threadIdx.x;
    const int lane = tid & 63;
    const int wv   = tid >> 6;      // 0..7
    const int g    = wv & 3;        // pos-group
    const int h    = wv >> 2;       // K-half
    const int hi   = lane >> 5;
    const int l31  = lane & 31;
    const int wsel = h << 1;        // XOR remap of oc blocks per half

    const int bid  = blockIdx.x;    // 576 = 8 imgs * 72 tiles
    const int bimg = bid & 7;       // XCD k -> image k (L2 locality)
    const int rem  = bid >> 3;      // 0..71
    const int h0   = (rem / 6) * 8; // block tile: 8 rows x 16 cols
    const int w0   = (rem % 6) * 16;

    const int r0 = h0 + g*2 + (l31 >> 4);
    const int c0 = w0 + (l31 & 15);

    const char* xbase = (const char*)(xp + (size_t)bimg*PIMG + (size_t)(h*32)*PCH);
    const int voff0 = (r0*PW + c0) * 4;

    f32x16 acc[4];
#pragma unroll
    for (int os = 0; os < 4; os++)
#pragma unroll
        for (int r = 0; r < 16; r++) acc[os][r] = 0.f;

    // prologue: stage step-0 slab for my half (4 waves x 4 rows = 16 KB)
    {
        const char* wsrc = (const char*)wb + (size_t)(h*32)*CHB;
#pragma unroll
        for (int i = 0; i < 4; i++) {
            const int m = i*4 + g;
            gload_lds16(wsrc + m*1024 + lane*16, &sw[h][0][0] + m*1024);
        }
    }
    __syncthreads();

#pragma unroll 1
    for (int t = 0; t < 32; t++) {
        char* bufc = &sw[h][t & 1][0];
        // 1) R loads for THIS step's channel (issued FIRST so their waitcnt
        //    doesn't drain the staging queue)
        const char* xc = xbase + (size_t)t*(PCH*4);
        float q[9];
#pragma unroll
        for (int j = 0; j < 3; j++) {
            f32x4 R = (f32x4)*(const f32x4u*)(xc + voff0 + j*(PW*4));
            q[j*3 + 0] = R[0]; q[j*3 + 1] = R[1]; q[j*3 + 2] = R[2];
        }
        // 2) stage next slab (stays in flight until the end-of-step barrier)
        if (t + 1 < 32) {
            const char* wsrc = (const char*)wb + (size_t)(h*32 + t + 1)*CHB;
            char* bufn = &sw[h][(t + 1) & 1][0];
#pragma unroll
            for (int i = 0; i < 4; i++) {
                const int m = i*4 + g;
                gload_lds16(wsrc + m*1024 + lane*16, bufn + m*1024);
            }
        }
        // 3) per-kc: A ds_reads + B build + 4 MFMA (A regs recycled each kc)
        {
            bf16x8 A[4];
#pragma unroll
            for (int os = 0; os < 4; os++)
                A[os] = *(const bf16x8*)(bufc + (0*2 + hi)*2048 + (((os^wsel)*32) + l31)*16);
            bf16x8 tb = mkfrag<0>(q, hi);
#pragma unroll
            for (int os = 0; os < 4; os++)
                acc[os] = __builtin_amdgcn_mfma_f32_32x32x16_bf16(A[os], tb, acc[os], 0, 0, 0);
        }
        {
            bf16x8 A[4];
#pragma unroll
            for (int os = 0; os < 4; os++)
                A[os] = *(const bf16x8*)(bufc + (1*2 + hi)*2048 + (((os^wsel)*32) + l31)*16);
            bf16x8 tb = mkfrag<1>(q, hi);
#pragma unroll
            for (int os = 0; os < 4; os++)
                acc[os] = __builtin_amdgcn_mfma_f32_32x32x16_bf16(A[os], tb, acc[os], 0, 0, 0);
        }
        {
            bf16x8 A[4];
#pragma unroll
            for (int os = 0; os < 4; os++)
                A[os] = *(const bf16x8*)(bufc + (2*2 + hi)*2048 + (((os^wsel)*32) + l31)*16);
            bf16x8 tb = mkfrag<2>(q, hi);
#pragma unroll
            for (int os = 0; os < 4; os++)
                acc[os] = __builtin_amdgcn_mfma_f32_32x32x16_bf16(A[os], tb, acc[os], 0, 0, 0);
        }
        {
            bf16x8 A[4];
#pragma unroll
            for (int os = 0; os < 4; os++)
                A[os] = *(const bf16x8*)(bufc + (3*2 + hi)*2048 + (((os^wsel)*32) + l31)*16);
            bf16x8 tb = mkfrag<3>(q, hi);
#pragma unroll
            for (int os = 0; os < 4; os++)
                acc[os] = __builtin_amdgcn_mfma_f32_32x32x16_bf16(A[os], tb, acc[os], 0, 0, 0);
        }
        // 4) barrier: my slab reads done + stage(t+1) landed (vmcnt drains here)
        __syncthreads();
    }

    // ---- K-combine with partner wave (wv^4). Each wave STORES local acc[2],
    // acc[3] (partner's global oc blocks) and ADDS partner's contribution into
    // acc[0],acc[1]. Slot g2 holds acc[2+(g2>>2)] regs (g2&3)*4..+3. All
    // indices compile-time; lane*16 layout -> conflict-free.
    {
        char* lred = &sw[0][0][0];     // reuse 64 KB slab space
        char* my = lred + wv*8192;
#pragma unroll
        for (int g2 = 0; g2 < 8; g2++) {
            f32x4 v;
            v[0] = acc[2 + (g2>>2)][(g2&3)*4 + 0];
            v[1] = acc[2 + (g2>>2)][(g2&3)*4 + 1];
            v[2] = acc[2 + (g2>>2)][(g2&3)*4 + 2];
            v[3] = acc[2 + (g2>>2)][(g2&3)*4 + 3];
            *(f32x4*)(my + g2*1024 + lane*16) = v;
        }
        __syncthreads();
        const char* ot = lred + (wv ^ 4)*8192;
#pragma unroll
        for (int g2 = 0; g2 < 8; g2++) {
            f32x4 v = *(const f32x4*)(ot + g2*1024 + lane*16);
            acc[g2>>2][(g2&3)*4 + 0] += v[0];
            acc[g2>>2][(g2&3)*4 + 1] += v[1];
            acc[g2>>2][(g2&3)*4 + 2] += v[2];
            acc[g2>>2][(g2&3)*4 + 3] += v[3];
        }
    }

    // epilogue: write local acc[0],acc[1] -> global oc blocks (osl ^ wsel)
    const size_t obase = (size_t)bimg*OCH*HW*HW + (size_t)r0*HW + c0;
#pragma unroll
    for (int osl = 0; osl < 2; osl++) {
        const int gblk = osl ^ wsel;
#pragma unroll
        for (int r = 0; r < 16; r++) {
            const int oc = gblk*32 + (r & 3) + 8*(r >> 2) + 4*hi;
            out[obase + (size_t)oc*(HW*HW)] = acc[osl][r];
        }
    }
}

// ---------- fallback (no pad buffer): round-8 register-path kernel
__global__ __launch_bounds__(64, 3) void socg_fb(const float* __restrict__ x,
                                                 const __bf16* __restrict__ wb,
                                                 float* __restrict__ out) {
    const int lane = threadIdx.x;
    const int hi   = lane >> 5;
    const int l31  = lane & 31;

    const int bid  = blockIdx.x;
    const int bimg = bid / 288;
    const int rem  = bid - bimg * 288;
    const int h0   = (rem / 6) * 2;
    const int w0   = (rem % 6) * 16;

    const int hA = h0 + (l31 >> 4);
    const int wA = w0 + (l31 & 15);

    int   off[9];
    float msk[9];
#pragma unroll
    for (int rr = 0; rr < 3; rr++)
#pragma unroll
        for (int cc = 0; cc < 3; cc++) {
            int hh = hA - 1 + rr, ww = wA - 1 + cc;
            bool ok = ((unsigned)hh < HW) && ((unsigned)ww < HW);
            int hc = hh < 0 ? 0 : (hh > HW-1 ? HW-1 : hh);
            int wc = ww < 0 ? 0 : (ww > HW-1 ? HW-1 : ww);
            off[rr*3 + cc] = hc * HW + wc;
            msk[rr*3 + cc] = ok ? 1.f : 0.f;
        }

    const float* xb = x + (size_t)bimg * CIN * HW * HW;

    f32x16 acc[4];
#pragma unroll
    for (int os = 0; os < 4; os++)
#pragma unroll
        for (int r = 0; r < 16; r++) acc[os][r] = 0.f;

    float rA[9], rB[9];
#pragma unroll
    for (int i = 0; i < 9; i++) rA[i] = xb[off[i]];

    auto loadA = [&](bf16x8 (&A)[4], const __bf16* wc_, int kc) {
#pragma unroll
        for (int os = 0; os < 4; os++)
            A[os] = *(const bf16x8*)(wc_ + (kc*2 + hi)*1024 + (os*32 + l31)*8);
    };

    auto body = [&](float (&rc)[9], float (&rn)[9], int c) {
        const __bf16* wc_ = wb + (size_t)c * 8192;
        bf16x8 A0[4], A1[4], A2[4], A3[4];
        loadA(A0, wc_, 0);
        loadA(A1, wc_, 1);
        loadA(A2, wc_, 2);
        loadA(A3, wc_, 3);
        if (c + 1 < CIN) {
            const float* xn = xb + (size_t)(c + 1) * HW * HW;
#pragma unroll
            for (int i = 0; i < 9; i++) rn[i] = xn[off[i]];
        }
        float q[9];
#pragma unroll
        for (int i = 0; i < 9; i++) q[i] = rc[i] * msk[i];

        {
            bf16x8 tb = mkfrag<0>(q, hi);
#pragma unroll
            for (int os = 0; os < 4; os++)
                acc[os] = __builtin_amdgcn_mfma_f32_32x32x16_bf16(A0[os], tb, acc[os], 0, 0, 0);
        }
        {
            bf16x8 tb = mkfrag<1>(q, hi);
#pragma unroll
            for (int os = 0; os < 4; os++)
                acc[os] = __builtin_amdgcn_mfma_f32_32x32x16_bf16(A1[os], tb, acc[os], 0, 0, 0);
        }
        {
            bf16x8 tb = mkfrag<2>(q, hi);
#pragma unroll
            for (int os = 0; os < 4; os++)
                acc[os] = __builtin_amdgcn_mfma_f32_32x32x16_bf16(A2[os], tb, acc[os], 0, 0, 0);
        }
        {
            bf16x8 tb = mkfrag<3>(q, hi);
#pragma unroll
            for (int os = 0; os < 4; os++)
                acc[os] = __builtin_amdgcn_mfma_f32_32x32x16_bf16(A3[os], tb, acc[os], 0, 0, 0);
        }
    };

#pragma unroll 1
    for (int c2 = 0; c2 < CIN; c2 += 2) {
        body(rA, rB, c2);
        body(rB, rA, c2 + 1);
    }

#pragma unroll
    for (int os = 0; os < 4; os++)
#pragma unroll
        for (int r = 0; r < 16; r++) {
            int oc = os*32 + (r & 3) + 8*(r >> 2) + 4*hi;
            out[(((size_t)bimg*OCH + oc)*HW + hA)*HW + wA] = acc[os][r];
        }
}

extern "C" void kernel_launch(void* const* d_in, const int* in_sizes, int n_in,
                              void* d_out, int out_size, void* d_ws, size_t ws_size,
                              hipStream_t stream) {
    const float* x = (const float*)d_in[0];
    const float* w = (const float*)d_in[1];
    float* out = (float*)d_out;
    if (ws_size >= PAD_BYTES + WB_BYTES) {
        float* xpad = (float*)d_ws;
        __bf16* wbf = (__bf16*)((char*)d_ws + PAD_BYTES);
        hipLaunchKernelGGL(prep_pad, dim3(PAD_FLOATS/256), dim3(256), 0, stream, x, xpad);
        hipLaunchKernelGGL(prep_w, dim3(1024), dim3(256), 0, stream, w, wbf);
        hipLaunchKernelGGL(socg_ks, dim3(576), dim3(512), 0, stream, xpad, wbf, out);
    } else {
        __bf16* wbf = (__bf16*)d_ws;
        hipLaunchKernelGGL(prep_w, dim3(1024), dim3(256), 0, stream, w, wbf);
        hipLaunchKernelGGL(socg_fb, dim3(2304), dim3(64), 0, stream, x, wbf, out);
    }
}